// Round 11
// baseline (381.107 us; speedup 1.0000x reference)
//
#include <hip/hip_runtime.h>
#include <hip/hip_bf16.h>

typedef unsigned short ushort_t;
typedef unsigned int uint_t;
typedef __attribute__((ext_vector_type(8))) short bf16x8;
typedef __attribute__((ext_vector_type(4))) float f32x4;

#define MFMA32(a, b, c) __builtin_amdgcn_mfma_f32_16x16x32_bf16(a, b, c, 0, 0, 0)

static constexpr int BATCH = 16;
static constexpr int SEQ   = 4096;   // H*W
static constexpr int CH    = 128;
static constexpr int NGRP  = 32;
static constexpr float EPS = 1e-6f;
// softmax scale folded into exp2 domain AND pre-folded into Q projection:
static constexpr float C2 = 0.08838834764831845f * 1.4426950408889634f;

__device__ inline ushort_t f2bf(float f) {
    uint_t u = __float_as_uint(f);
    u = (u + 0x7fff + ((u >> 16) & 1)) >> 16;
    return (ushort_t)u;
}

// ---------------- GroupNorm partial sums (fp32 input) ----------------
// grid 256 = batch(16) x chunk(16); block 256. Writes RAW (sum, sumsq).
__global__ void gn_partial(const float* __restrict__ x, float* __restrict__ stats) {
    int bid = blockIdx.x;
    int b = bid >> 4, chunk = bid & 15;
    int t = threadIdx.x;
    int c4 = (t & 31) * 4;   // one group = 4 channels
    int rowoff = t >> 5;     // 0..7
    const float* xb = x + (size_t)b * SEQ * CH;
    float s1 = 0.f, s2 = 0.f;
    int base_row = chunk * 256;
    for (int i = 0; i < 32; ++i) {
        int r = base_row + i * 8 + rowoff;
        float4 v = *(const float4*)(xb + (size_t)r * CH + c4);
        s1 += v.x + v.y + v.z + v.w;
        s2 += v.x * v.x + v.y * v.y + v.z * v.z + v.w * v.w;
    }
    __shared__ float red[256][2];
    red[t][0] = s1; red[t][1] = s2;
    __syncthreads();
    if (t < 32) {
        float a1 = 0.f, a2 = 0.f;
        for (int ro = 0; ro < 8; ++ro) {
            a1 += red[ro * 32 + t][0];
            a2 += red[ro * 32 + t][1];
        }
        atomicAdd(&stats[(b * NGRP + t) * 2 + 0], a1);
        atomicAdd(&stats[(b * NGRP + t) * 2 + 1], a2);
    }
}

// ---------------- fused normalize + QKV GEMM (finalize inlined) ----------------
// q output pre-scaled by C2; v written TRANSPOSED: vt[b][d][seq]
__global__ __launch_bounds__(256) void gemm_qkv(const float* __restrict__ x,
                                                const float* __restrict__ stats,
                                                const float* __restrict__ gsc,
                                                const float* __restrict__ gbi,
                                                const float* __restrict__ Wq,
                                                const float* __restrict__ Wk,
                                                const float* __restrict__ Wv,
                                                const float* __restrict__ Bq,
                                                const float* __restrict__ Bk,
                                                const float* __restrict__ Bv,
                                                ushort_t* __restrict__ outq,
                                                ushort_t* __restrict__ outk,
                                                ushort_t* __restrict__ outvt) {
    __shared__ ushort_t lds_a[128][136];  // full 128x128 normalized A tile (bf16)
    __shared__ ushort_t lds_w[128][72];   // W^T half-tile [n][k_local]
    __shared__ float2 gstat[32];
    int t = threadIdx.x;
    int wv = t >> 6, lane = t & 63, quad = lane >> 4, l16 = lane & 15;
    size_t m0 = (size_t)blockIdx.x * 128;
    int batch = (int)(m0 >> 12);
    int seq0  = (int)(m0 & 4095);
    // inline gn_finalize for this batch
    if (t < 32) {
        float sum = stats[(batch * NGRP + t) * 2 + 0];
        float sq  = stats[(batch * NGRP + t) * 2 + 1];
        float mean = sum / 16384.f;
        float var  = sq / 16384.f - mean * mean;
        gstat[t] = float2{mean, __frsqrt_rn(var + EPS)};
    }
    __syncthreads();
    // stage A once, normalizing x -> h in flight
    for (int i = 0; i < 8; ++i) {
        int idx = (t + i * 256) * 8;
        int r = idx >> 7, c = idx & 127;
        size_t row = m0 + r;
        float4 xa = *(const float4*)(x + row * CH + c);
        float4 xc = *(const float4*)(x + row * CH + c + 4);
        float2 stA = gstat[c >> 2];
        float2 stB = gstat[(c >> 2) + 1];
        float4 sA = *(const float4*)(gsc + c), sB = *(const float4*)(gsc + c + 4);
        float4 bA = *(const float4*)(gbi + c), bB = *(const float4*)(gbi + c + 4);
        ushort_t tmp[8];
        tmp[0] = f2bf((xa.x - stA.x) * stA.y * sA.x + bA.x);
        tmp[1] = f2bf((xa.y - stA.x) * stA.y * sA.y + bA.y);
        tmp[2] = f2bf((xa.z - stA.x) * stA.y * sA.z + bA.z);
        tmp[3] = f2bf((xa.w - stA.x) * stA.y * sA.w + bA.w);
        tmp[4] = f2bf((xc.x - stB.x) * stB.y * sB.x + bB.x);
        tmp[5] = f2bf((xc.y - stB.x) * stB.y * sB.y + bB.y);
        tmp[6] = f2bf((xc.z - stB.x) * stB.y * sB.z + bB.z);
        tmp[7] = f2bf((xc.w - stB.x) * stB.y * sB.w + bB.w);
        *(uint4*)&lds_a[r][c] = *(const uint4*)tmp;
    }
    for (int j = 0; j < 3; ++j) {
        const float* W  = (j == 0) ? Wq : (j == 1) ? Wk : Wv;
        const float* Bi = (j == 0) ? Bq : (j == 1) ? Bk : Bv;
        f32x4 acc[2][8] = {};
        for (int kh = 0; kh < 2; ++kh) {
            int k0 = kh * 64;
            __syncthreads();   // protect lds_w reuse (also orders A staging before first read)
            for (int i = 0; i < 8; ++i) {
                int idx = (t + i * 256) * 4;     // flat = kl*128 + n
                int kl = idx >> 7, n = idx & 127;
                float4 wf = *(const float4*)(W + (size_t)(k0 + kl) * CH + n);
                lds_w[n + 0][kl] = f2bf(wf.x);
                lds_w[n + 1][kl] = f2bf(wf.y);
                lds_w[n + 2][kl] = f2bf(wf.z);
                lds_w[n + 3][kl] = f2bf(wf.w);
            }
            __syncthreads();
            for (int ks = 0; ks < 2; ++ks) {
                bf16x8 afrag[2];
                for (int tr = 0; tr < 2; ++tr)
                    afrag[tr] = *(const bf16x8*)&lds_a[wv * 32 + tr * 16 + l16][k0 + ks * 32 + quad * 8];
                for (int tc = 0; tc < 8; ++tc) {
                    bf16x8 bfrag = *(const bf16x8*)&lds_w[tc * 16 + l16][ks * 32 + quad * 8];
                    for (int tr = 0; tr < 2; ++tr)
                        acc[tr][tc] = MFMA32(afrag[tr], bfrag, acc[tr][tc]);
                }
            }
        }
        // epilogue
        for (int tc = 0; tc < 8; ++tc) {
            int col = tc * 16 + l16;
            float bval = Bi[col];
            for (int tr = 0; tr < 2; ++tr) {
                int rl = wv * 32 + tr * 16 + quad * 4;
                for (int r = 0; r < 4; ++r) {
                    float vv = acc[tr][tc][r] + bval;
                    if (j == 0) vv *= C2;   // fold softmax scale into q
                    if (j == 2) {
                        outvt[(size_t)batch * CH * SEQ + (size_t)col * SEQ + seq0 + rl + r] = f2bf(vv);
                    } else {
                        ushort_t* op = (j == 0) ? outq : outk;
                        op[(m0 + rl + r) * CH + col] = f2bf(vv);
                    }
                }
            }
        }
    }
}

// ---------------- flash attention: nt=2 LDS amortization + MFMA32 PV + lazy ----
// grid 512: b = bid & 15 (L2-pinned), qt = bid >> 4. Block = 256 threads (4 waves),
// each wave owns 32 q-rows (nt=2) -> kf/vf LDS fragments feed 2x the MFMA,
// halving LDS read traffic per FLOP (LDS was the dominant pipe at nt=1).
// launch_bounds(256,3): 170-reg cap; peak live ~164 regs -> no spill (tripwire:
// FETCH >> 100 MB means spill -> revert). V^T columns permuted at staging so
// S^T C-layout P, packed via memcpy, is directly the MFMA32 B-operand (r9/r10).
__global__ __launch_bounds__(256, 3) void flash_attn9(const ushort_t* __restrict__ q,
                                                      const ushort_t* __restrict__ k,
                                                      const ushort_t* __restrict__ vt,
                                                      ushort_t* __restrict__ o) {
    int bid = blockIdx.x;
    int b = bid & 15, qt = bid >> 4;
    int t = threadIdx.x;
    int wv = t >> 6, lane = t & 63, quad = lane >> 4, l16 = lane & 15;
    const size_t SB = (size_t)SEQ * CH;
    const ushort_t* qb  = q  + (size_t)b * SB;
    const ushort_t* kb  = k  + (size_t)b * SB;
    const ushort_t* vtb = vt + (size_t)b * SB;   // [d][seq]

    __shared__ ushort_t lds_k[64][136];    // [key][d]
    __shared__ ushort_t lds_vt[128][72];   // [d][key_local PERMUTED]

    int qrow_base = qt * 128 + wv * 32;
    // Q^T B-fragments (n=qrow=l16, k=d=quad*8+j)
    bf16x8 qfrag[2][4];
    for (int nt = 0; nt < 2; ++nt)
        for (int ks = 0; ks < 4; ++ks)
            qfrag[nt][ks] = *(const bf16x8*)(qb + (size_t)(qrow_base + nt * 16 + l16) * CH + ks * 32 + quad * 8);

    f32x4 oacc[8][2] = {};    // [mt=d/16][nt]
    float mref[2] = {-1e30f, -1e30f};
    float lsum[2] = {0.f, 0.f};

    for (int it = 0; it < 64; ++it) {
        int key0 = it * 64;
        __syncthreads();
        // stage K tile (64 keys x 128 d), row-major, b128
        for (int i = 0; i < 4; ++i) {
            int idx = (t + i * 256) * 8;
            int r = idx >> 7, c = idx & 127;
            *(uint4*)&lds_k[r][c] = *(const uint4*)(kb + (size_t)(key0 + r) * CH + c);
        }
        // stage V^T tile (128 d x 64 keys) with PV column permutation:
        // source key g = 32a+16e+4q+r  ->  dest col c = 32a+8q+4e+r
        for (int i = 0; i < 4; ++i) {
            int idx = (t + i * 256) * 8;
            int d = idx >> 6;
            int beta = (idx >> 3) & 7;
            uint4 vv = *(const uint4*)(vtb + (size_t)d * SEQ + key0 + beta * 8);
            int c0 = 32 * (beta >> 2) + 16 * (beta & 1) + 4 * ((beta >> 1) & 1);
            *(uint2*)&lds_vt[d][c0]     = uint2{vv.x, vv.y};
            *(uint2*)&lds_vt[d][c0 + 8] = uint2{vv.z, vv.w};
        }
        __syncthreads();

        // S^T = K·Q^T : per wave 64 keys x 32 qrows (q pre-scaled by C2)
        f32x4 s[4][2] = {};   // [kt][nt]
        for (int ks = 0; ks < 4; ++ks) {
            bf16x8 kf[4];
            for (int kt = 0; kt < 4; ++kt)
                kf[kt] = *(const bf16x8*)&lds_k[kt * 16 + l16][ks * 32 + quad * 8];
            for (int kt = 0; kt < 4; ++kt)
                for (int nt = 0; nt < 2; ++nt)
                    s[kt][nt] = MFMA32(kf[kt], qfrag[nt][ks], s[kt][nt]);
        }

        // lazy online softmax (exp2 domain): rescale only when the tile max
        // exceeds the running reference by >30 (wave-voted; ~once per kernel)
        bf16x8 pkp[2][2];   // [ktp][nt]
        for (int nt = 0; nt < 2; ++nt) {
            float mt_ = -1e30f;
            for (int kt = 0; kt < 4; ++kt)
                for (int r = 0; r < 4; ++r)
                    mt_ = fmaxf(mt_, s[kt][nt][r]);
            mt_ = fmaxf(mt_, __shfl_xor(mt_, 16, 64));
            mt_ = fmaxf(mt_, __shfl_xor(mt_, 32, 64));
            if (__any(mt_ > mref[nt] + 30.f)) {
                float mnew = fmaxf(mref[nt], mt_);
                float alpha = exp2f(mref[nt] - mnew);
                lsum[nt] *= alpha;
                for (int mt = 0; mt < 8; ++mt)
                    for (int r = 0; r < 4; ++r)
                        oacc[mt][nt][r] *= alpha;
                mref[nt] = mnew;
            }
            float ps = 0.f;
            uint_t pb[8];
            for (int kt = 0; kt < 4; ++kt) {
                float p0 = exp2f(s[kt][nt][0] - mref[nt]);
                float p1 = exp2f(s[kt][nt][1] - mref[nt]);
                float p2 = exp2f(s[kt][nt][2] - mref[nt]);
                float p3 = exp2f(s[kt][nt][3] - mref[nt]);
                ps += (p0 + p1) + (p2 + p3);
                __hip_bfloat162 h01 = __float22bfloat162_rn(float2{p0, p1});
                __hip_bfloat162 h23 = __float22bfloat162_rn(float2{p2, p3});
                __builtin_memcpy(&pb[kt * 2 + 0], &h01, 4);
                __builtin_memcpy(&pb[kt * 2 + 1], &h23, 4);
            }
            ps += __shfl_xor(ps, 16, 64);
            ps += __shfl_xor(ps, 32, 64);
            lsum[nt] += ps;
            __builtin_memcpy(&pkp[0][nt], &pb[0], 16);
            __builtin_memcpy(&pkp[1][nt], &pb[4], 16);
        }

        // O^T += V^T · P^T via MFMA32; vf shared across both nt (the payoff)
        for (int mt = 0; mt < 8; ++mt) {
            bf16x8 vf0 = *(const bf16x8*)&lds_vt[mt * 16 + l16][quad * 8];
            bf16x8 vf1 = *(const bf16x8*)&lds_vt[mt * 16 + l16][32 + quad * 8];
            oacc[mt][0] = MFMA32(vf0, pkp[0][0], oacc[mt][0]);
            oacc[mt][1] = MFMA32(vf0, pkp[0][1], oacc[mt][1]);
            oacc[mt][0] = MFMA32(vf1, pkp[1][0], oacc[mt][0]);
            oacc[mt][1] = MFMA32(vf1, pkp[1][1], oacc[mt][1]);
        }
    }

    // epilogue: O[qrow][d] = O^T / l  (8B stores)
    for (int nt = 0; nt < 2; ++nt) {
        float inv = 1.f / lsum[nt];
        size_t row = (size_t)b * SEQ + qrow_base + nt * 16 + l16;
        for (int mt = 0; mt < 8; ++mt) {
            ushort_t tmp[4];
            for (int r = 0; r < 4; ++r) tmp[r] = f2bf(oacc[mt][nt][r] * inv);
            *(uint2*)&o[row * CH + mt * 16 + quad * 4] = *(const uint2*)tmp;
        }
    }
}

// ---------------- final GEMM: out = A_bf16 @ W + bias + resid (fp32 out) ----------------
__global__ __launch_bounds__(256) void gemm_out(const ushort_t* __restrict__ A,
                                                const float* __restrict__ W,
                                                const float* __restrict__ bias,
                                                const float* __restrict__ resid,
                                                float* __restrict__ out) {
    __shared__ ushort_t lds_a[128][72];
    __shared__ ushort_t lds_w[128][72];
    int t = threadIdx.x;
    int wv = t >> 6, lane = t & 63, quad = lane >> 4, l16 = lane & 15;
    size_t m0 = (size_t)blockIdx.x * 128;
    f32x4 acc[2][8] = {};
    for (int kh = 0; kh < 2; ++kh) {
        int k0 = kh * 64;
        __syncthreads();
        for (int i = 0; i < 4; ++i) {
            int idx = (t + i * 256) * 8;
            int r = idx >> 6, c = idx & 63;
            *(uint4*)&lds_a[r][c] = *(const uint4*)(A + (m0 + r) * CH + k0 + c);
        }
        for (int i = 0; i < 8; ++i) {
            int idx = (t + i * 256) * 4;
            int kl = idx >> 7, n = idx & 127;
            float4 wf = *(const float4*)(W + (size_t)(k0 + kl) * CH + n);
            lds_w[n + 0][kl] = f2bf(wf.x);
            lds_w[n + 1][kl] = f2bf(wf.y);
            lds_w[n + 2][kl] = f2bf(wf.z);
            lds_w[n + 3][kl] = f2bf(wf.w);
        }
        __syncthreads();
        for (int ks = 0; ks < 2; ++ks) {
            bf16x8 afrag[2];
            for (int tr = 0; tr < 2; ++tr)
                afrag[tr] = *(const bf16x8*)&lds_a[wv * 32 + tr * 16 + l16][ks * 32 + quad * 8];
            for (int tc = 0; tc < 8; ++tc) {
                bf16x8 bfrag = *(const bf16x8*)&lds_w[tc * 16 + l16][ks * 32 + quad * 8];
                for (int tr = 0; tr < 2; ++tr)
                    acc[tr][tc] = MFMA32(afrag[tr], bfrag, acc[tr][tc]);
            }
        }
    }
    for (int tc = 0; tc < 8; ++tc) {
        int col = tc * 16 + l16;
        float bval = bias[col];
        for (int tr = 0; tr < 2; ++tr) {
            int rl = wv * 32 + tr * 16 + quad * 4;
            for (int r = 0; r < 4; ++r) {
                size_t row = m0 + rl + r;
                out[row * CH + col] = acc[tr][tc][r] + bval + resid[row * CH + col];
            }
        }
    }
}

extern "C" void kernel_launch(void* const* d_in, const int* in_sizes, int n_in,
                              void* d_out, int out_size, void* d_ws, size_t ws_size,
                              hipStream_t stream) {
    const float* x   = (const float*)d_in[0];
    const float* gsc = (const float*)d_in[1];
    const float* gbi = (const float*)d_in[2];
    const float* wq  = (const float*)d_in[3];
    const float* bq  = (const float*)d_in[4];
    const float* wk  = (const float*)d_in[5];
    const float* bk  = (const float*)d_in[6];
    const float* wvp = (const float*)d_in[7];
    const float* bv  = (const float*)d_in[8];
    const float* wo  = (const float*)d_in[9];
    const float* bo  = (const float*)d_in[10];
    float* outp = (float*)d_out;

    const size_t NELEM = (size_t)BATCH * SEQ * CH;  // 8388608
    float*    stats = (float*)d_ws;
    ushort_t* qbuf  = (ushort_t*)((char*)d_ws + 4096);
    ushort_t* kbuf  = qbuf + NELEM;
    ushort_t* vtbuf = kbuf + NELEM;
    ushort_t* abuf  = vtbuf + NELEM;   // attention output

    hipMemsetAsync(stats, 0, BATCH * NGRP * 2 * sizeof(float), stream);
    gn_partial<<<256, 256, 0, stream>>>(x, stats);
    gemm_qkv<<<512, 256, 0, stream>>>(x, stats, gsc, gbi, wq, wk, wvp, bq, bk, bv,
                                      qbuf, kbuf, vtbuf);
    flash_attn9<<<512, 256, 0, stream>>>(qbuf, kbuf, vtbuf, abuf);
    gemm_out<<<512, 256, 0, stream>>>(abuf, wo, bo, x, outp);
}

// Round 12
// 358.418 us; speedup vs baseline: 1.0633x; 1.0633x over previous
//
#include <hip/hip_runtime.h>
#include <hip/hip_bf16.h>

typedef unsigned short ushort_t;
typedef unsigned int uint_t;
typedef __attribute__((ext_vector_type(8))) short bf16x8;
typedef __attribute__((ext_vector_type(4))) float f32x4;

#define MFMA32(a, b, c) __builtin_amdgcn_mfma_f32_16x16x32_bf16(a, b, c, 0, 0, 0)

static constexpr int BATCH = 16;
static constexpr int SEQ   = 4096;   // H*W
static constexpr int CH    = 128;
static constexpr int NGRP  = 32;
static constexpr float EPS = 1e-6f;
// softmax scale folded into exp2 domain AND pre-folded into Q projection:
static constexpr float C2 = 0.08838834764831845f * 1.4426950408889634f;

__device__ inline ushort_t f2bf(float f) {
    uint_t u = __float_as_uint(f);
    u = (u + 0x7fff + ((u >> 16) & 1)) >> 16;
    return (ushort_t)u;
}

// ---------------- GroupNorm partial sums (fp32 input) ----------------
// grid 256 = batch(16) x chunk(16); block 256. Writes RAW (sum, sumsq).
__global__ void gn_partial(const float* __restrict__ x, float* __restrict__ stats) {
    int bid = blockIdx.x;
    int b = bid >> 4, chunk = bid & 15;
    int t = threadIdx.x;
    int c4 = (t & 31) * 4;   // one group = 4 channels
    int rowoff = t >> 5;     // 0..7
    const float* xb = x + (size_t)b * SEQ * CH;
    float s1 = 0.f, s2 = 0.f;
    int base_row = chunk * 256;
    for (int i = 0; i < 32; ++i) {
        int r = base_row + i * 8 + rowoff;
        float4 v = *(const float4*)(xb + (size_t)r * CH + c4);
        s1 += v.x + v.y + v.z + v.w;
        s2 += v.x * v.x + v.y * v.y + v.z * v.z + v.w * v.w;
    }
    __shared__ float red[256][2];
    red[t][0] = s1; red[t][1] = s2;
    __syncthreads();
    if (t < 32) {
        float a1 = 0.f, a2 = 0.f;
        for (int ro = 0; ro < 8; ++ro) {
            a1 += red[ro * 32 + t][0];
            a2 += red[ro * 32 + t][1];
        }
        atomicAdd(&stats[(b * NGRP + t) * 2 + 0], a1);
        atomicAdd(&stats[(b * NGRP + t) * 2 + 1], a2);
    }
}

// ---------------- fused normalize + QKV GEMM (finalize inlined) ----------------
// q output pre-scaled by C2; v written TRANSPOSED: vt[b][d][seq]
__global__ __launch_bounds__(256) void gemm_qkv(const float* __restrict__ x,
                                                const float* __restrict__ stats,
                                                const float* __restrict__ gsc,
                                                const float* __restrict__ gbi,
                                                const float* __restrict__ Wq,
                                                const float* __restrict__ Wk,
                                                const float* __restrict__ Wv,
                                                const float* __restrict__ Bq,
                                                const float* __restrict__ Bk,
                                                const float* __restrict__ Bv,
                                                ushort_t* __restrict__ outq,
                                                ushort_t* __restrict__ outk,
                                                ushort_t* __restrict__ outvt) {
    __shared__ ushort_t lds_a[128][136];  // full 128x128 normalized A tile (bf16)
    __shared__ ushort_t lds_w[128][72];   // W^T half-tile [n][k_local]
    __shared__ float2 gstat[32];
    int t = threadIdx.x;
    int wv = t >> 6, lane = t & 63, quad = lane >> 4, l16 = lane & 15;
    size_t m0 = (size_t)blockIdx.x * 128;
    int batch = (int)(m0 >> 12);
    int seq0  = (int)(m0 & 4095);
    // inline gn_finalize for this batch
    if (t < 32) {
        float sum = stats[(batch * NGRP + t) * 2 + 0];
        float sq  = stats[(batch * NGRP + t) * 2 + 1];
        float mean = sum / 16384.f;
        float var  = sq / 16384.f - mean * mean;
        gstat[t] = float2{mean, __frsqrt_rn(var + EPS)};
    }
    __syncthreads();
    // stage A once, normalizing x -> h in flight
    for (int i = 0; i < 8; ++i) {
        int idx = (t + i * 256) * 8;
        int r = idx >> 7, c = idx & 127;
        size_t row = m0 + r;
        float4 xa = *(const float4*)(x + row * CH + c);
        float4 xc = *(const float4*)(x + row * CH + c + 4);
        float2 stA = gstat[c >> 2];
        float2 stB = gstat[(c >> 2) + 1];
        float4 sA = *(const float4*)(gsc + c), sB = *(const float4*)(gsc + c + 4);
        float4 bA = *(const float4*)(gbi + c), bB = *(const float4*)(gbi + c + 4);
        ushort_t tmp[8];
        tmp[0] = f2bf((xa.x - stA.x) * stA.y * sA.x + bA.x);
        tmp[1] = f2bf((xa.y - stA.x) * stA.y * sA.y + bA.y);
        tmp[2] = f2bf((xa.z - stA.x) * stA.y * sA.z + bA.z);
        tmp[3] = f2bf((xa.w - stA.x) * stA.y * sA.w + bA.w);
        tmp[4] = f2bf((xc.x - stB.x) * stB.y * sB.x + bB.x);
        tmp[5] = f2bf((xc.y - stB.x) * stB.y * sB.y + bB.y);
        tmp[6] = f2bf((xc.z - stB.x) * stB.y * sB.z + bB.z);
        tmp[7] = f2bf((xc.w - stB.x) * stB.y * sB.w + bB.w);
        *(uint4*)&lds_a[r][c] = *(const uint4*)tmp;
    }
    for (int j = 0; j < 3; ++j) {
        const float* W  = (j == 0) ? Wq : (j == 1) ? Wk : Wv;
        const float* Bi = (j == 0) ? Bq : (j == 1) ? Bk : Bv;
        f32x4 acc[2][8] = {};
        for (int kh = 0; kh < 2; ++kh) {
            int k0 = kh * 64;
            __syncthreads();   // protect lds_w reuse (also orders A staging before first read)
            for (int i = 0; i < 8; ++i) {
                int idx = (t + i * 256) * 4;     // flat = kl*128 + n
                int kl = idx >> 7, n = idx & 127;
                float4 wf = *(const float4*)(W + (size_t)(k0 + kl) * CH + n);
                lds_w[n + 0][kl] = f2bf(wf.x);
                lds_w[n + 1][kl] = f2bf(wf.y);
                lds_w[n + 2][kl] = f2bf(wf.z);
                lds_w[n + 3][kl] = f2bf(wf.w);
            }
            __syncthreads();
            for (int ks = 0; ks < 2; ++ks) {
                bf16x8 afrag[2];
                for (int tr = 0; tr < 2; ++tr)
                    afrag[tr] = *(const bf16x8*)&lds_a[wv * 32 + tr * 16 + l16][k0 + ks * 32 + quad * 8];
                for (int tc = 0; tc < 8; ++tc) {
                    bf16x8 bfrag = *(const bf16x8*)&lds_w[tc * 16 + l16][ks * 32 + quad * 8];
                    for (int tr = 0; tr < 2; ++tr)
                        acc[tr][tc] = MFMA32(afrag[tr], bfrag, acc[tr][tc]);
                }
            }
        }
        // epilogue
        for (int tc = 0; tc < 8; ++tc) {
            int col = tc * 16 + l16;
            float bval = Bi[col];
            for (int tr = 0; tr < 2; ++tr) {
                int rl = wv * 32 + tr * 16 + quad * 4;
                for (int r = 0; r < 4; ++r) {
                    float vv = acc[tr][tc][r] + bval;
                    if (j == 0) vv *= C2;   // fold softmax scale into q
                    if (j == 2) {
                        outvt[(size_t)batch * CH * SEQ + (size_t)col * SEQ + seq0 + rl + r] = f2bf(vv);
                    } else {
                        ushort_t* op = (j == 0) ? outq : outk;
                        op[(m0 + rl + r) * CH + col] = f2bf(vv);
                    }
                }
            }
        }
    }
}

// ---------------- flash attention: r10 + LDS double-buffer (1 barrier/iter) ----
// grid 512: b = bid & 15 (L2-pinned), qt = bid >> 4. Block = 512 threads (8 waves),
// each wave owns 16 q-rows (nt=1) -> 16 waves/CU (r11 showed nt=2 at 8 waves/CU
// loses more to exposed latency than it saves in LDS traffic).
// Double-buffered K/V tiles (71.7 KB, 2 blocks/CU): write tile i+1 into buffer
// ~p while computing from p -> ONE barrier per iteration instead of two.
// V^T columns permuted at staging so S^T C-layout P (packed via memcpy) is
// directly the MFMA32 B-operand (r9/r10-proven). Lazy softmax (r6/r7/r10-proven).
__global__ __launch_bounds__(512, 4) void flash_attn10(const ushort_t* __restrict__ q,
                                                       const ushort_t* __restrict__ k,
                                                       const ushort_t* __restrict__ vt,
                                                       ushort_t* __restrict__ o) {
    int bid = blockIdx.x;
    int b = bid & 15, qt = bid >> 4;
    int t = threadIdx.x;
    int wv = t >> 6, lane = t & 63, quad = lane >> 4, l16 = lane & 15;
    const size_t SB = (size_t)SEQ * CH;
    const ushort_t* qb  = q  + (size_t)b * SB;
    const ushort_t* kb  = k  + (size_t)b * SB;
    const ushort_t* vtb = vt + (size_t)b * SB;   // [d][seq]

    __shared__ ushort_t lds_k[2][64][136];    // [buf][key][d]
    __shared__ ushort_t lds_vt[2][128][72];   // [buf][d][key_local PERMUTED]

    int qrow_base = qt * 128 + wv * 16;
    // Q^T B-fragments (n=qrow=l16, k=d=quad*8+j)
    bf16x8 qfrag[4];
    for (int ks = 0; ks < 4; ++ks)
        qfrag[ks] = *(const bf16x8*)(qb + (size_t)(qrow_base + l16) * CH + ks * 32 + quad * 8);

    f32x4 oacc[8] = {};    // [mt=d/16]
    float mref = -1e30f;
    float lsum = 0.f;

    // staging geometry (fixed per thread)
    int kr_row0 = t >> 4, kr_row1 = 32 + (t >> 4);
    int kr_col  = (t & 15) * 8;
    int vr_d0 = t >> 3, vr_d1 = 64 + (t >> 3);
    int vr_beta = t & 7;
    int vc0 = 32 * (vr_beta >> 2) + 16 * (vr_beta & 1) + 4 * ((vr_beta >> 1) & 1);

    const ushort_t* kp0 = kb + (size_t)kr_row0 * CH + kr_col;
    const ushort_t* kp1 = kb + (size_t)kr_row1 * CH + kr_col;
    const ushort_t* vp0 = vtb + (size_t)vr_d0 * SEQ + vr_beta * 8;
    const ushort_t* vp1 = vtb + (size_t)vr_d1 * SEQ + vr_beta * 8;

    // preload tile 0 -> regs -> buf 0
    uint4 kr0 = *(const uint4*)kp0;  kp0 += 64 * CH;
    uint4 kr1 = *(const uint4*)kp1;  kp1 += 64 * CH;
    uint4 vr0 = *(const uint4*)vp0;  vp0 += 64;
    uint4 vr1 = *(const uint4*)vp1;  vp1 += 64;
    *(uint4*)&lds_k[0][kr_row0][kr_col] = kr0;
    *(uint4*)&lds_k[0][kr_row1][kr_col] = kr1;
    *(uint2*)&lds_vt[0][vr_d0][vc0]     = uint2{vr0.x, vr0.y};
    *(uint2*)&lds_vt[0][vr_d0][vc0 + 8] = uint2{vr0.z, vr0.w};
    *(uint2*)&lds_vt[0][vr_d1][vc0]     = uint2{vr1.x, vr1.y};
    *(uint2*)&lds_vt[0][vr_d1][vc0 + 8] = uint2{vr1.z, vr1.w};
    __syncthreads();

    for (int it = 0; it < 64; ++it) {
        int cur = it & 1;
        // prefetch tile it+1 -> regs (at it=63 overruns into the adjacent
        // workspace buffer; values never used)
        kr0 = *(const uint4*)kp0;  kp0 += 64 * CH;
        kr1 = *(const uint4*)kp1;  kp1 += 64 * CH;
        vr0 = *(const uint4*)vp0;  vp0 += 64;
        vr1 = *(const uint4*)vp1;  vp1 += 64;

        // S^T = K·Q^T : per wave 64 keys x 16 qrows (q pre-scaled by C2)
        f32x4 s[4] = {};   // [kt]
        for (int ks = 0; ks < 4; ++ks) {
            bf16x8 kf[4];
            for (int kt = 0; kt < 4; ++kt)
                kf[kt] = *(const bf16x8*)&lds_k[cur][kt * 16 + l16][ks * 32 + quad * 8];
            for (int kt = 0; kt < 4; ++kt)
                s[kt] = MFMA32(kf[kt], qfrag[ks], s[kt]);
        }

        // lazy online softmax (exp2 domain): rescale only when the tile max
        // exceeds the running reference by >30 (wave-voted; ~once per kernel)
        bf16x8 pkp0, pkp1;
        {
            float mt_ = -1e30f;
            for (int kt = 0; kt < 4; ++kt)
                for (int r = 0; r < 4; ++r)
                    mt_ = fmaxf(mt_, s[kt][r]);
            mt_ = fmaxf(mt_, __shfl_xor(mt_, 16, 64));
            mt_ = fmaxf(mt_, __shfl_xor(mt_, 32, 64));
            if (__any(mt_ > mref + 30.f)) {
                float mnew = fmaxf(mref, mt_);
                float alpha = exp2f(mref - mnew);
                lsum *= alpha;
                for (int mt = 0; mt < 8; ++mt)
                    for (int r = 0; r < 4; ++r)
                        oacc[mt][r] *= alpha;
                mref = mnew;
            }
            float ps = 0.f;
            uint_t pb[8];
            for (int kt = 0; kt < 4; ++kt) {
                float p0 = exp2f(s[kt][0] - mref);
                float p1 = exp2f(s[kt][1] - mref);
                float p2 = exp2f(s[kt][2] - mref);
                float p3 = exp2f(s[kt][3] - mref);
                ps += (p0 + p1) + (p2 + p3);
                __hip_bfloat162 h01 = __float22bfloat162_rn(float2{p0, p1});
                __hip_bfloat162 h23 = __float22bfloat162_rn(float2{p2, p3});
                __builtin_memcpy(&pb[kt * 2 + 0], &h01, 4);
                __builtin_memcpy(&pb[kt * 2 + 1], &h23, 4);
            }
            ps += __shfl_xor(ps, 16, 64);
            ps += __shfl_xor(ps, 32, 64);
            lsum += ps;
            __builtin_memcpy(&pkp0, &pb[0], 16);
            __builtin_memcpy(&pkp1, &pb[4], 16);
        }

        // O^T += V^T · P^T  via MFMA32 (V^T columns pre-permuted to match pkp)
        for (int mt = 0; mt < 8; ++mt) {
            bf16x8 vf0 = *(const bf16x8*)&lds_vt[cur][mt * 16 + l16][quad * 8];
            bf16x8 vf1 = *(const bf16x8*)&lds_vt[cur][mt * 16 + l16][32 + quad * 8];
            oacc[mt] = MFMA32(vf0, pkp0, oacc[mt]);
            oacc[mt] = MFMA32(vf1, pkp1, oacc[mt]);
        }

        // write prefetched tile -> other buffer (read last at iter it-1;
        // the barrier below orders it for iter it+1)
        int nxt = cur ^ 1;
        *(uint4*)&lds_k[nxt][kr_row0][kr_col] = kr0;
        *(uint4*)&lds_k[nxt][kr_row1][kr_col] = kr1;
        *(uint2*)&lds_vt[nxt][vr_d0][vc0]     = uint2{vr0.x, vr0.y};
        *(uint2*)&lds_vt[nxt][vr_d0][vc0 + 8] = uint2{vr0.z, vr0.w};
        *(uint2*)&lds_vt[nxt][vr_d1][vc0]     = uint2{vr1.x, vr1.y};
        *(uint2*)&lds_vt[nxt][vr_d1][vc0 + 8] = uint2{vr1.z, vr1.w};
        __syncthreads();   // single barrier per iteration
    }

    // epilogue: O[qrow][d] = O^T / l  (8B stores)
    float inv = 1.f / lsum;
    size_t row = (size_t)b * SEQ + qrow_base + l16;
    for (int mt = 0; mt < 8; ++mt) {
        ushort_t tmp[4];
        for (int r = 0; r < 4; ++r) tmp[r] = f2bf(oacc[mt][r] * inv);
        *(uint2*)&o[row * CH + mt * 16 + quad * 4] = *(const uint2*)tmp;
    }
}

// ---------------- final GEMM: out = A_bf16 @ W + bias + resid (fp32 out) ----------------
__global__ __launch_bounds__(256) void gemm_out(const ushort_t* __restrict__ A,
                                                const float* __restrict__ W,
                                                const float* __restrict__ bias,
                                                const float* __restrict__ resid,
                                                float* __restrict__ out) {
    __shared__ ushort_t lds_a[128][72];
    __shared__ ushort_t lds_w[128][72];
    int t = threadIdx.x;
    int wv = t >> 6, lane = t & 63, quad = lane >> 4, l16 = lane & 15;
    size_t m0 = (size_t)blockIdx.x * 128;
    f32x4 acc[2][8] = {};
    for (int kh = 0; kh < 2; ++kh) {
        int k0 = kh * 64;
        __syncthreads();
        for (int i = 0; i < 4; ++i) {
            int idx = (t + i * 256) * 8;
            int r = idx >> 6, c = idx & 63;
            *(uint4*)&lds_a[r][c] = *(const uint4*)(A + (m0 + r) * CH + k0 + c);
        }
        for (int i = 0; i < 8; ++i) {
            int idx = (t + i * 256) * 4;
            int kl = idx >> 7, n = idx & 127;
            float4 wf = *(const float4*)(W + (size_t)(k0 + kl) * CH + n);
            lds_w[n + 0][kl] = f2bf(wf.x);
            lds_w[n + 1][kl] = f2bf(wf.y);
            lds_w[n + 2][kl] = f2bf(wf.z);
            lds_w[n + 3][kl] = f2bf(wf.w);
        }
        __syncthreads();
        for (int ks = 0; ks < 2; ++ks) {
            bf16x8 afrag[2];
            for (int tr = 0; tr < 2; ++tr)
                afrag[tr] = *(const bf16x8*)&lds_a[wv * 32 + tr * 16 + l16][ks * 32 + quad * 8];
            for (int tc = 0; tc < 8; ++tc) {
                bf16x8 bfrag = *(const bf16x8*)&lds_w[tc * 16 + l16][ks * 32 + quad * 8];
                for (int tr = 0; tr < 2; ++tr)
                    acc[tr][tc] = MFMA32(afrag[tr], bfrag, acc[tr][tc]);
            }
        }
    }
    for (int tc = 0; tc < 8; ++tc) {
        int col = tc * 16 + l16;
        float bval = bias[col];
        for (int tr = 0; tr < 2; ++tr) {
            int rl = wv * 32 + tr * 16 + quad * 4;
            for (int r = 0; r < 4; ++r) {
                size_t row = m0 + rl + r;
                out[row * CH + col] = acc[tr][tc][r] + bval + resid[row * CH + col];
            }
        }
    }
}

extern "C" void kernel_launch(void* const* d_in, const int* in_sizes, int n_in,
                              void* d_out, int out_size, void* d_ws, size_t ws_size,
                              hipStream_t stream) {
    const float* x   = (const float*)d_in[0];
    const float* gsc = (const float*)d_in[1];
    const float* gbi = (const float*)d_in[2];
    const float* wq  = (const float*)d_in[3];
    const float* bq  = (const float*)d_in[4];
    const float* wk  = (const float*)d_in[5];
    const float* bk  = (const float*)d_in[6];
    const float* wvp = (const float*)d_in[7];
    const float* bv  = (const float*)d_in[8];
    const float* wo  = (const float*)d_in[9];
    const float* bo  = (const float*)d_in[10];
    float* outp = (float*)d_out;

    const size_t NELEM = (size_t)BATCH * SEQ * CH;  // 8388608
    float*    stats = (float*)d_ws;
    ushort_t* qbuf  = (ushort_t*)((char*)d_ws + 4096);
    ushort_t* kbuf  = qbuf + NELEM;
    ushort_t* vtbuf = kbuf + NELEM;
    ushort_t* abuf  = vtbuf + NELEM;   // attention output
    // note: flash_attn10 prefetches one tile past K/V^T ends (reads land in the
    // adjacent workspace buffer; values unused) — keep abuf allocated after vtbuf.

    hipMemsetAsync(stats, 0, BATCH * NGRP * 2 * sizeof(float), stream);
    gn_partial<<<256, 256, 0, stream>>>(x, stats);
    gemm_qkv<<<512, 256, 0, stream>>>(x, stats, gsc, gbi, wq, wk, wvp, bq, bk, bv,
                                      qbuf, kbuf, vtbuf);
    flash_attn10<<<512, 512, 0, stream>>>(qbuf, kbuf, vtbuf, abuf);
    gemm_out<<<512, 256, 0, stream>>>(abuf, wo, bo, x, outp);
}